// Round 2
// 2233.022 us; speedup vs baseline: 6.6395x; 6.6395x over previous
//
#include <hip/hip_runtime.h>
#include <hip/hip_bf16.h>

#define EPSF 1e-5f

typedef unsigned short u16;
typedef __attribute__((ext_vector_type(8))) short short8v;   // 8 bf16 bits (4 VGPRs)
typedef __attribute__((ext_vector_type(4))) float f32x4;

// ---------------------------------------------------------------------------
// Module-scope scratch. 51.2M floats = 204.8 MB, lifetime-aliased.
// Map (floats):
//   [       0,10240000) img_seq -> hbuf(bf16 80000x512) -> nhwc_hi(bf16 80000x384 = [0,15.36M))
//   [10240000,20480000) rad_seq -> (hbuf cont.)         -> (nhwc_hi cont.)
//   [20480000,30720000) score/idx -> qh -> x            -> nhwc_lo (bf16, [20.48M,35.84M))
//   [30720000,35840000) kh                               -> (nhwc_lo cont.)
//   [35840000,40960000) vh                               -> wgt_hi/wgt_lo (bf16 384x9x384 each,
//                                                           [35.84M,37.17M); vh dead after attn)
//   [40960000,51200000) fbuf(kvn/qn/o/xn) -> rad_e (2x128x40000, LIVE until convert_nhwc done)
// d_out written ONLY by conv + bn_relu. d_ws unused. d_in never written.
// NOTE (R1 fix): wgt_* was previously at 46080000, inside rad_e's live range —
// prep_weights clobbered rad_e[b=1] before convert_nhwc read it (absmax 1.54).
// ---------------------------------------------------------------------------
__device__ float g_arena[51200000];
__device__ float g_stats[768];

// ---------------------------------------------------------------------------
// helpers
// ---------------------------------------------------------------------------
__device__ __forceinline__ float wave_sum(float v) {
#pragma unroll
    for (int o = 32; o > 0; o >>= 1) v += __shfl_down(v, o, 64);
    return v;
}

__device__ __forceinline__ float dot4(float4 a, float4 b) {
    return a.x * b.x + a.y * b.y + a.z * b.z + a.w * b.w;
}

__device__ __forceinline__ unsigned short bfbits(float x) {
    __hip_bfloat16 h = __float2bfloat16(x);
    return *reinterpret_cast<unsigned short*>(&h);
}

__device__ __forceinline__ float to_f(float x) { return x; }
__device__ __forceinline__ float to_f(__hip_bfloat16 x) { return __bfloat162float(x); }

__device__ __forceinline__ void store4(float* p, float4 r) { *(float4*)p = r; }
__device__ __forceinline__ void store4(__hip_bfloat16* p, float4 r) {
    ushort4 u = make_ushort4(bfbits(r.x), bfbits(r.y), bfbits(r.z), bfbits(r.w));
    *reinterpret_cast<ushort4*>(p) = u;
}

// split fp32 -> bf16 hi + bf16 lo (lo = bf16(x - fp32(hi))); residual ~2^-17 rel
__device__ __forceinline__ void bf_split(float v, u16& h, u16& l) {
    __hip_bfloat16 bh = __float2bfloat16(v);
    float hv = __bfloat162float(bh);
    __hip_bfloat16 bl = __float2bfloat16(v - hv);
    h = *reinterpret_cast<u16*>(&bh);
    l = *reinterpret_cast<u16*>(&bl);
}

// ---------------------------------------------------------------------------
// gemm128: out[p][ocb+oc] = sum_c A[p][c] * W[ocb+oc][c]  (+bias,+resid,relu)
// ---------------------------------------------------------------------------
template <typename TIN, typename TOUT>
__global__ __launch_bounds__(256) void gemm128_kernel(
    const TIN* __restrict__ A, const float* __restrict__ W,
    const float* __restrict__ bias, const float* __restrict__ resid,
    TOUT* __restrict__ out, int Cin, int Nout, int feat_mode, int relu_flag)
{
    __shared__ float sa[16][68];
    __shared__ float sw[16][132];

    const int tid = threadIdx.x;
    const int p0 = blockIdx.x * 64;
    const int ocb = blockIdx.y * 128;
    const int oc_g = tid & 31;
    const int pos_g = tid >> 5;
    const int oc0 = oc_g * 4;
    const int pp0 = pos_g * 8;

    float acc[4][8];
#pragma unroll
    for (int a = 0; a < 4; a++)
#pragma unroll
        for (int j = 0; j < 8; j++) acc[a][j] = 0.f;

    const int bb = p0 / 40000;
    const int hw0 = p0 % 40000;

    for (int cb = 0; cb < Cin; cb += 16) {
        __syncthreads();
        if (feat_mode) {
#pragma unroll
            for (int i = 0; i < 4; i++) {
                int e = tid + i * 256;
                int cc = e >> 6, pos = e & 63;
                sa[cc][pos] = to_f(A[((size_t)bb * Cin + cb + cc) * 40000 + hw0 + pos]);
            }
        } else {
#pragma unroll
            for (int i = 0; i < 4; i++) {
                int e = tid + i * 256;
                int pos = e >> 4, cc = e & 15;
                sa[cc][pos] = to_f(A[(size_t)(p0 + pos) * Cin + cb + cc]);
            }
        }
#pragma unroll
        for (int i = 0; i < 8; i++) {
            int e = tid + i * 256;
            int oc = e >> 4, cc = e & 15;
            sw[cc][oc] = W[(size_t)(ocb + oc) * Cin + cb + cc];
        }
        __syncthreads();
#pragma unroll
        for (int cc = 0; cc < 16; cc++) {
            float4 wv = *(const float4*)&sw[cc][oc0];
            float4 a0 = *(const float4*)&sa[cc][pp0];
            float4 a1 = *(const float4*)&sa[cc][pp0 + 4];
            float av[8] = {a0.x, a0.y, a0.z, a0.w, a1.x, a1.y, a1.z, a1.w};
            float wr[4] = {wv.x, wv.y, wv.z, wv.w};
#pragma unroll
            for (int jj = 0; jj < 4; jj++)
#pragma unroll
                for (int j = 0; j < 8; j++)
                    acc[jj][j] += wr[jj] * av[j];
        }
    }

    float bv[4] = {0.f, 0.f, 0.f, 0.f};
    if (bias) {
#pragma unroll
        for (int jj = 0; jj < 4; jj++) bv[jj] = bias[ocb + oc0 + jj];
    }
#pragma unroll
    for (int j = 0; j < 8; j++) {
        size_t row = (size_t)(p0 + pp0 + j) * Nout + ocb + oc0;
        float4 r;
        r.x = acc[0][j] + bv[0];
        r.y = acc[1][j] + bv[1];
        r.z = acc[2][j] + bv[2];
        r.w = acc[3][j] + bv[3];
        if (resid) {
            float4 rr = *(const float4*)&resid[row];
            r.x += rr.x; r.y += rr.y; r.z += rr.z; r.w += rr.w;
        }
        if (relu_flag) {
            r.x = fmaxf(r.x, 0.f); r.y = fmaxf(r.y, 0.f);
            r.z = fmaxf(r.z, 0.f); r.w = fmaxf(r.w, 0.f);
        }
        store4(&out[row], r);
    }
}

// ---------------------------------------------------------------------------
// score: h = relu(si @ W1^T + b1) (64), score = h @ w2 + b2
// ---------------------------------------------------------------------------
__global__ __launch_bounds__(256) void score_kernel(
    const float* __restrict__ rad_seq, const float* __restrict__ img_seq,
    const float* __restrict__ w1, const float* __restrict__ b1,
    const float* __restrict__ w2, const float* __restrict__ b2,
    float* __restrict__ score)
{
    __shared__ float sw1[64][20];
    __shared__ float ss[16][20];
    const int tid = threadIdx.x;
    const int p0 = blockIdx.x * 16;
    const int wvid = tid >> 6;
    const int l = tid & 63;
    float acc[4] = {0.f, 0.f, 0.f, 0.f};

    for (int cb = 0; cb < 256; cb += 16) {
        __syncthreads();
#pragma unroll
        for (int i = 0; i < 4; i++) {
            int e = tid + i * 256;
            int ll = e >> 4, cc = e & 15;
            sw1[ll][cc] = w1[(size_t)ll * 256 + cb + cc];
        }
        {
            int pos = tid >> 4, cc = tid & 15;
            int c = cb + cc;
            ss[pos][cc] = (c < 128)
                ? rad_seq[(size_t)(p0 + pos) * 128 + c]
                : img_seq[(size_t)(p0 + pos) * 128 + (c - 128)];
        }
        __syncthreads();
#pragma unroll
        for (int c4 = 0; c4 < 4; c4++) {
            float4 wv = *(const float4*)&sw1[l][c4 * 4];
#pragma unroll
            for (int j = 0; j < 4; j++) {
                float4 sv = *(const float4*)&ss[wvid * 4 + j][c4 * 4];
                acc[j] += dot4(wv, sv);
            }
        }
    }
    float b1v = b1[l], w2v = w2[l], b2v = b2[0];
#pragma unroll
    for (int j = 0; j < 4; j++) {
        float h = fmaxf(acc[j] + b1v, 0.f);
        float v = wave_sum(h * w2v);
        if (l == 0) score[p0 + wvid * 4 + j] = v + b2v;
    }
}

// ---------------------------------------------------------------------------
// topk: exact stable rank selection (matches jax.lax.top_k tie-breaking)
// ---------------------------------------------------------------------------
__global__ __launch_bounds__(256) void topk_kernel(
    const float* __restrict__ score, int* __restrict__ idx)
{
    __shared__ float s[200];
    const int n = blockIdx.x;
    const int t = threadIdx.x;
    if (t < 200) s[t] = score[(size_t)n * 200 + t];
    __syncthreads();
    if (t < 200) {
        float my = s[t];
        int cnt = 0;
        for (int j = 0; j < 200; j++) {
            float o = s[j];
            cnt += (o > my) || (o == my && j < t);
        }
        if (cnt < 100) idx[n * 100 + cnt] = t;
    }
}

// ---------------------------------------------------------------------------
// ln_gather: out[r][:] = LN(in[src_row][:]) * g + b  over 128 channels
// ---------------------------------------------------------------------------
__global__ __launch_bounds__(256) void ln_gather_kernel(
    const float* __restrict__ in, const int* __restrict__ gidx,
    const float* __restrict__ g, const float* __restrict__ bb,
    float* __restrict__ out)
{
    __shared__ float red[4];
    const int tid = threadIdx.x;
    const int grp = tid >> 7;
    const int t = tid & 127;
    const int r = blockIdx.x * 2 + grp;

    size_t src_row;
    if (gidx) src_row = (size_t)(r / 100) * 200 + gidx[r];
    else      src_row = (size_t)r;

    float x = in[src_row * 128 + t];
    float s = wave_sum(x);
    if ((tid & 63) == 0) red[tid >> 6] = s;
    __syncthreads();
    float m = (red[grp * 2] + red[grp * 2 + 1]) * 0.0078125f;
    float d = x - m;
    float s2 = wave_sum(d * d);
    __syncthreads();
    if ((tid & 63) == 0) red[tid >> 6] = s2;
    __syncthreads();
    float var = (red[grp * 2] + red[grp * 2 + 1]) * 0.0078125f;
    out[(size_t)r * 128 + t] = d * rsqrtf(var + EPSF) * g[t] + bb[t];
}

// ---------------------------------------------------------------------------
// attention: block = (head h, row n); thread = one query w (<200)
// ---------------------------------------------------------------------------
__global__ __launch_bounds__(256) void attention_kernel(
    const float* __restrict__ qh, const float* __restrict__ kh,
    const float* __restrict__ vh, float* __restrict__ o)
{
    __shared__ float sk[100][16];
    __shared__ float sv[100][16];
    const int h = blockIdx.x;
    const int n = blockIdx.y;
    const int tid = threadIdx.x;

    for (int e = tid; e < 1600; e += 256) {
        int kk = e >> 4, d = e & 15;
        size_t src = ((size_t)n * 100 + kk) * 128 + h * 16 + d;
        sk[kk][d] = kh[src];
        sv[kk][d] = vh[src];
    }
    __syncthreads();

    if (tid < 200) {
        const float* qp = &qh[((size_t)n * 200 + tid) * 128 + h * 16];
        float4 q0 = *(const float4*)(qp + 0);
        float4 q1 = *(const float4*)(qp + 4);
        float4 q2 = *(const float4*)(qp + 8);
        float4 q3 = *(const float4*)(qp + 12);

        float m = -INFINITY, l = 0.f;
        float4 a0 = {0,0,0,0}, a1 = {0,0,0,0}, a2 = {0,0,0,0}, a3 = {0,0,0,0};

        for (int kk = 0; kk < 100; kk++) {
            const float4* kp = (const float4*)&sk[kk][0];
            float s = dot4(q0, kp[0]) + dot4(q1, kp[1]) +
                      dot4(q2, kp[2]) + dot4(q3, kp[3]);
            s *= 0.25f;
            float nm = fmaxf(m, s);
            float corr = __expf(m - nm);
            float pe = __expf(s - nm);
            l = l * corr + pe;
            const float4* vp = (const float4*)&sv[kk][0];
            float4 v0 = vp[0], v1 = vp[1], v2 = vp[2], v3 = vp[3];
            a0.x = a0.x * corr + pe * v0.x; a0.y = a0.y * corr + pe * v0.y;
            a0.z = a0.z * corr + pe * v0.z; a0.w = a0.w * corr + pe * v0.w;
            a1.x = a1.x * corr + pe * v1.x; a1.y = a1.y * corr + pe * v1.y;
            a1.z = a1.z * corr + pe * v1.z; a1.w = a1.w * corr + pe * v1.w;
            a2.x = a2.x * corr + pe * v2.x; a2.y = a2.y * corr + pe * v2.y;
            a2.z = a2.z * corr + pe * v2.z; a2.w = a2.w * corr + pe * v2.w;
            a3.x = a3.x * corr + pe * v3.x; a3.y = a3.y * corr + pe * v3.y;
            a3.z = a3.z * corr + pe * v3.z; a3.w = a3.w * corr + pe * v3.w;
            m = nm;
        }
        float inv = 1.f / l;
        float* op = &o[((size_t)n * 200 + tid) * 128 + h * 16];
        a0.x *= inv; a0.y *= inv; a0.z *= inv; a0.w *= inv;
        a1.x *= inv; a1.y *= inv; a1.z *= inv; a1.w *= inv;
        a2.x *= inv; a2.y *= inv; a2.z *= inv; a2.w *= inv;
        a3.x *= inv; a3.y *= inv; a3.z *= inv; a3.w *= inv;
        *(float4*)(op + 0)  = a0;
        *(float4*)(op + 4)  = a1;
        *(float4*)(op + 8)  = a2;
        *(float4*)(op + 12) = a3;
    }
}

// ---------------------------------------------------------------------------
// enhance: delta = x @ Wd^T; gate = sigmoid((radar,image) @ Wg^T + gb) * rmask
// rad_e = radar + gamma*gate*rmask*delta   (d_in untouched)
// ---------------------------------------------------------------------------
__global__ __launch_bounds__(256) void enhance_kernel(
    const float* __restrict__ x, const float* __restrict__ radar,
    const float* __restrict__ image, const float* __restrict__ wd,
    const float* __restrict__ wg, const float* __restrict__ gb,
    const float* __restrict__ gamma_p, float* __restrict__ rad_e)
{
    __shared__ float sa[16][68];
    __shared__ float sw[16][132];
    const int tid = threadIdx.x;
    const int b = blockIdx.y;
    const int hw0 = blockIdx.x * 64;
    const int p0 = b * 40000 + hw0;
    const int oc_g = tid & 31, pos_g = tid >> 5;
    const int oc0 = oc_g * 4, pp0 = pos_g * 8;

    float accd[4][8] = {};
    float accg[4][8] = {};

    // phase 1: delta over x [p][128]
    for (int cb = 0; cb < 128; cb += 16) {
        __syncthreads();
#pragma unroll
        for (int i = 0; i < 4; i++) {
            int e = tid + i * 256;
            int pos = e >> 4, cc = e & 15;
            sa[cc][pos] = x[(size_t)(p0 + pos) * 128 + cb + cc];
        }
#pragma unroll
        for (int i = 0; i < 8; i++) {
            int e = tid + i * 256;
            int oc = e >> 4, cc = e & 15;
            sw[cc][oc] = wd[(size_t)oc * 128 + cb + cc];
        }
        __syncthreads();
#pragma unroll
        for (int cc = 0; cc < 16; cc++) {
            float4 wv = *(const float4*)&sw[cc][oc0];
            float4 b0 = *(const float4*)&sa[cc][pp0];
            float4 b1 = *(const float4*)&sa[cc][pp0 + 4];
            float av[8] = {b0.x, b0.y, b0.z, b0.w, b1.x, b1.y, b1.z, b1.w};
            float wr[4] = {wv.x, wv.y, wv.z, wv.w};
#pragma unroll
            for (int jj = 0; jj < 4; jj++)
#pragma unroll
                for (int j = 0; j < 8; j++)
                    accd[jj][j] += wr[jj] * av[j];
        }
    }
    // phase 2: gate over concat(radar, image) NCHW feat, Cin=384
    for (int cb = 0; cb < 384; cb += 16) {
        __syncthreads();
        const float* src = (cb < 128)
            ? radar + ((size_t)b * 128 + cb) * 40000
            : image + ((size_t)b * 256 + (cb - 128)) * 40000;
#pragma unroll
        for (int i = 0; i < 4; i++) {
            int e = tid + i * 256;
            int cc = e >> 6, pos = e & 63;
            sa[cc][pos] = src[(size_t)cc * 40000 + hw0 + pos];
        }
#pragma unroll
        for (int i = 0; i < 8; i++) {
            int e = tid + i * 256;
            int oc = e >> 4, cc = e & 15;
            sw[cc][oc] = wg[(size_t)oc * 384 + cb + cc];
        }
        __syncthreads();
#pragma unroll
        for (int cc = 0; cc < 16; cc++) {
            float4 wv = *(const float4*)&sw[cc][oc0];
            float4 b0 = *(const float4*)&sa[cc][pp0];
            float4 b1 = *(const float4*)&sa[cc][pp0 + 4];
            float av[8] = {b0.x, b0.y, b0.z, b0.w, b1.x, b1.y, b1.z, b1.w};
            float wr[4] = {wv.x, wv.y, wv.z, wv.w};
#pragma unroll
            for (int jj = 0; jj < 4; jj++)
#pragma unroll
                for (int j = 0; j < 8; j++)
                    accg[jj][j] += wr[jj] * av[j];
        }
    }

    const float gmm = gamma_p[0];
#pragma unroll
    for (int jj = 0; jj < 4; jj++) {
        int oc = oc0 + jj;
        float gbv = gb[oc];
#pragma unroll
        for (int j = 0; j < 8; j++) {
            int hw = hw0 + pp0 + j;
            int hrow = hw / 200;
            float rm = fmaxf(0.3f, 1.0f - 0.7f * ((float)hrow * (1.0f / 199.0f)));
            float gsig = 1.f / (1.f + __expf(-(accg[jj][j] + gbv)));
            size_t ridx = ((size_t)b * 128 + oc) * 40000 + hw;
            rad_e[ridx] = radar[ridx] + gmm * gsig * rm * accd[jj][j];
        }
    }
}

// ---------------------------------------------------------------------------
// prep_weights: fuse_w [oc][ic][ky][kx] fp32 -> wr_hi/wr_lo [oc][s][ic] bf16
// (s = ky*3+kx). Lanes write consecutive ic -> coalesced stores.
// ---------------------------------------------------------------------------
__global__ __launch_bounds__(256) void prep_weights_kernel(
    const float* __restrict__ fw, u16* __restrict__ wh, u16* __restrict__ wl)
{
    int idx = blockIdx.x * 256 + threadIdx.x;   // < 384*384 = 147456
    int oc = idx / 384;
    int ic = idx - oc * 384;
    const float* src = fw + (size_t)idx * 9;
    u16* dh = wh + (size_t)oc * 3456 + ic;
    u16* dl = wl + (size_t)oc * 3456 + ic;
#pragma unroll
    for (int s = 0; s < 9; ++s) {
        u16 hh, ll;
        bf_split(src[s], hh, ll);
        dh[(size_t)s * 384] = hh;
        dl[(size_t)s * 384] = ll;
    }
}

// ---------------------------------------------------------------------------
// convert_nhwc: concat(rad_e[0:128], image[0:256]) NCHW fp32 -> NHWC bf16
// hi/lo planes [b*40000+hw][384]. Lane reads are coalesced (consecutive hw).
// ---------------------------------------------------------------------------
__global__ __launch_bounds__(256) void convert_nhwc_kernel(
    const float* __restrict__ rad_e, const float* __restrict__ image,
    u16* __restrict__ oh, u16* __restrict__ ol)
{
    int p = blockIdx.x * 256 + threadIdx.x;
    if (p >= 80000) return;
    int b = p >= 40000 ? 1 : 0;
    int hw = p - b * 40000;
    u16* ph = oh + (size_t)p * 384;
    u16* pl = ol + (size_t)p * 384;
#pragma unroll 1
    for (int g = 0; g < 48; ++g) {
        short8v vh, vl;
#pragma unroll
        for (int j = 0; j < 8; ++j) {
            int c = g * 8 + j;
            float v = (c < 128)
                ? rad_e[((size_t)(b * 128 + c)) * 40000 + hw]
                : image[((size_t)(b * 256 + (c - 128))) * 40000 + hw];
            u16 hh, ll;
            bf_split(v, hh, ll);
            vh[j] = (short)hh;
            vl[j] = (short)ll;
        }
        *(short8v*)&ph[g * 8] = vh;
        *(short8v*)&pl[g * 8] = vl;
    }
}

// ---------------------------------------------------------------------------
// conv_mfma: 3x3 SAME conv as 9 shifted GEMMs on matrix cores.
// Split-precision bf16: c = Ah*Bh + Ah*Bl + Al*Bh (fp32 accum), residual ~1e-5.
// Block: 128 oc (M) x 128 pos (N), 4 waves of 64x64. K-step = 64 ic.
// LDS tiles [row][ic] with XOR chunk swizzle: slot = chunk ^ (row&7) ->
// ds_read_b128/write_b128 are 2-way (free). Boundary masking at staging.
// MFMA frag layout (m89/m97-verified): A: row=l&15,k=(l>>4)*8+j (contig);
// B^T: col=l&15, same k; D: col=l&15 (pos), row=(l>>4)*4+reg (oc).
// ---------------------------------------------------------------------------
__global__ __launch_bounds__(256, 2) void conv_mfma_kernel(
    const u16* __restrict__ nhwc_hi, const u16* __restrict__ nhwc_lo,
    const u16* __restrict__ wgt_hi,  const u16* __restrict__ wgt_lo,
    float* __restrict__ out)
{
    __shared__ alignas(16) u16 sAh[8192], sAl[8192], sBh[8192], sBl[8192];  // 4 x 16 KB

    const int tid  = threadIdx.x;
    const int lane = tid & 63;
    const int wid  = tid >> 6;
    const int wrm  = wid >> 1;          // wave oc-half (0..1)
    const int wcn  = wid & 1;           // wave pos-half (0..1)
    const int hw0  = blockIdx.x * 128;
    const int b    = blockIdx.y;
    const int oc0  = blockIdx.z * 128;

    const int r0  = tid >> 3;           // staging row base 0..31
    const int cl  = tid & 7;            // staging chunk column
    const int swz = cl ^ (r0 & 7);      // swizzled slot (row&7 == r0&7 for all 4 rows)

    const int y0 = hw0 / 200;
    const int x0 = hw0 - y0 * 200;

    f32x4 acc[4][4];
#pragma unroll
    for (int i = 0; i < 4; ++i)
#pragma unroll
        for (int j = 0; j < 4; ++j) acc[i][j] = (f32x4){0.f, 0.f, 0.f, 0.f};

    size_t abase[4];
#pragma unroll
    for (int k = 0; k < 4; ++k)
        abase[k] = (size_t)(oc0 + r0 + k * 32) * 3456 + cl * 8;

    const int fr = lane & 15;           // fragment row-in-subtile
    const int fc = lane >> 4;           // fragment k-chunk / oc-quad selector

    for (int s = 0; s < 9; ++s) {
        const int dy = s / 3 - 1;
        const int dx = s % 3 - 1;
        size_t bsrc[4];
        int bval[4];
#pragma unroll
        for (int k = 0; k < 4; ++k) {
            int row = r0 + k * 32;
            int hwo = hw0 + row;
            int xr  = x0 + row;
            int wrp = (xr >= 200) ? 1 : 0;
            int yy  = y0 + wrp + dy;
            int xx  = xr - wrp * 200 + dx;
            int v = (hwo < 40000) && ((unsigned)yy < 200u) && ((unsigned)xx < 200u);
            bval[k] = v;
            bsrc[k] = v ? ((size_t)(b * 40000 + yy * 200 + xx) * 384 + cl * 8) : 0;
        }
        const size_t wofs = (size_t)s * 384;

        for (int icb = 0; icb < 6; ++icb) {
            const int ic0 = icb * 64;
            __syncthreads();
#pragma unroll
            for (int k = 0; k < 4; ++k) {
                int di = (r0 + k * 32) * 64 + swz * 8;
                size_t ga = abase[k] + wofs + ic0;
                *(short8v*)&sAh[di] = *(const short8v*)&wgt_hi[ga];
                *(short8v*)&sAl[di] = *(const short8v*)&wgt_lo[ga];
                if (bval[k]) {
                    size_t gb = bsrc[k] + ic0;
                    *(short8v*)&sBh[di] = *(const short8v*)&nhwc_hi[gb];
                    *(short8v*)&sBl[di] = *(const short8v*)&nhwc_lo[gb];
                } else {
                    short8v z = {0, 0, 0, 0, 0, 0, 0, 0};
                    *(short8v*)&sBh[di] = z;
                    *(short8v*)&sBl[di] = z;
                }
            }
            __syncthreads();
#pragma unroll
            for (int h = 0; h < 2; ++h) {
                const int kc = h * 4 + fc;
                short8v bhf[4], blf[4];
#pragma unroll
                for (int nn = 0; nn < 4; ++nn) {
                    int row = wcn * 64 + nn * 16 + fr;
                    int idx = row * 64 + ((kc ^ (row & 7)) << 3);
                    bhf[nn] = *(const short8v*)&sBh[idx];
                    blf[nn] = *(const short8v*)&sBl[idx];
                }
#pragma unroll
                for (int mm = 0; mm < 4; ++mm) {
                    int row = wrm * 64 + mm * 16 + fr;
                    int idx = row * 64 + ((kc ^ (row & 7)) << 3);
                    short8v ahf = *(const short8v*)&sAh[idx];
                    short8v alf = *(const short8v*)&sAl[idx];
#pragma unroll
                    for (int nn = 0; nn < 4; ++nn)
                        acc[mm][nn] = __builtin_amdgcn_mfma_f32_16x16x32_bf16(
                            ahf, bhf[nn], acc[mm][nn], 0, 0, 0);
#pragma unroll
                    for (int nn = 0; nn < 4; ++nn)
                        acc[mm][nn] = __builtin_amdgcn_mfma_f32_16x16x32_bf16(
                            ahf, blf[nn], acc[mm][nn], 0, 0, 0);
#pragma unroll
                    for (int nn = 0; nn < 4; ++nn)
                        acc[mm][nn] = __builtin_amdgcn_mfma_f32_16x16x32_bf16(
                            alf, bhf[nn], acc[mm][nn], 0, 0, 0);
                }
            }
        }
    }

    // epilogue: D[row=oc][col=pos]; lanes 0-15 -> 16 consecutive pos (64B)
#pragma unroll
    for (int mm = 0; mm < 4; ++mm) {
        int oc = oc0 + wrm * 64 + mm * 16 + fc * 4;
#pragma unroll
        for (int nn = 0; nn < 4; ++nn) {
            int p = hw0 + wcn * 64 + nn * 16 + fr;
            if (p < 40000) {
                float* op = out + (size_t)(b * 384 + oc) * 40000 + p;
#pragma unroll
                for (int r = 0; r < 4; ++r)
                    op[(size_t)r * 40000] = acc[mm][nn][r];
            }
        }
    }
}

// ---------------------------------------------------------------------------
// conv_stats: per-channel sum / sumsq over (B,H,W) -> g_stats (no atomics)
// ---------------------------------------------------------------------------
__global__ __launch_bounds__(256) void conv_stats_kernel(const float* __restrict__ out)
{
    const int c = blockIdx.x;           // 0..383
    float s1 = 0.f, s2 = 0.f;
#pragma unroll
    for (int b = 0; b < 2; ++b) {
        const float4* pp = (const float4*)(out + (size_t)(b * 384 + c) * 40000);
        for (int i = threadIdx.x; i < 10000; i += 256) {
            float4 v = pp[i];
            s1 += v.x + v.y + v.z + v.w;
            s2 += v.x * v.x + v.y * v.y + v.z * v.z + v.w * v.w;
        }
    }
    s1 = wave_sum(s1);
    s2 = wave_sum(s2);
    __shared__ float r1[4], r2[4];
    if ((threadIdx.x & 63) == 0) {
        r1[threadIdx.x >> 6] = s1;
        r2[threadIdx.x >> 6] = s2;
    }
    __syncthreads();
    if (threadIdx.x == 0) {
        g_stats[c * 2]     = r1[0] + r1[1] + r1[2] + r1[3];
        g_stats[c * 2 + 1] = r2[0] + r2[1] + r2[2] + r2[3];
    }
}

// ---------------------------------------------------------------------------
// bn_relu: in-place on d_out (30,720,000 floats = 7,680,000 float4)
// ---------------------------------------------------------------------------
__global__ __launch_bounds__(256) void bn_relu_kernel(
    float* __restrict__ out, const float* __restrict__ g,
    const float* __restrict__ bb)
{
    int i = blockIdx.x * 256 + threadIdx.x;   // float4 index < 7,680,000
    int flat = i * 4;
    int oc = (flat / 40000) % 384;
    float m = g_stats[oc * 2] * (1.f / 80000.f);
    float v = g_stats[oc * 2 + 1] * (1.f / 80000.f) - m * m;
    float inv = rsqrtf(v + EPSF);
    float sc = g[oc] * inv;
    float sh = bb[oc] - m * sc;
    float4 c = ((float4*)out)[i];
    c.x = fmaxf(c.x * sc + sh, 0.f);
    c.y = fmaxf(c.y * sc + sh, 0.f);
    c.z = fmaxf(c.z * sc + sh, 0.f);
    c.w = fmaxf(c.w * sc + sh, 0.f);
    ((float4*)out)[i] = c;
}

// ---------------------------------------------------------------------------
// launch
// ---------------------------------------------------------------------------
extern "C" void kernel_launch(void* const* d_in, const int* in_sizes, int n_in,
                              void* d_out, int out_size, void* d_ws, size_t ws_size,
                              hipStream_t stream)
{
    (void)in_sizes; (void)n_in; (void)out_size; (void)d_ws; (void)ws_size;

    const float* radar      = (const float*)d_in[0];
    const float* image      = (const float*)d_in[1];
    const float* img_proj_w = (const float*)d_in[2];
    const float* rad_proj_w = (const float*)d_in[3];
    const float* in_proj_w  = (const float*)d_in[4];
    const float* in_proj_b  = (const float*)d_in[5];
    const float* out_proj_w = (const float*)d_in[6];
    const float* out_proj_b = (const float*)d_in[7];
    const float* ln1q_g     = (const float*)d_in[8];
    const float* ln1q_b     = (const float*)d_in[9];
    const float* ln1kv_g    = (const float*)d_in[10];
    const float* ln1kv_b    = (const float*)d_in[11];
    const float* ln2_g      = (const float*)d_in[12];
    const float* ln2_b      = (const float*)d_in[13];
    const float* ffn_w1     = (const float*)d_in[14];
    const float* ffn_b1     = (const float*)d_in[15];
    const float* ffn_w2     = (const float*)d_in[16];
    const float* ffn_b2     = (const float*)d_in[17];
    const float* score_w1   = (const float*)d_in[18];
    const float* score_b1   = (const float*)d_in[19];
    const float* score_w2   = (const float*)d_in[20];
    const float* score_b2   = (const float*)d_in[21];
    const float* rad_delta_w= (const float*)d_in[22];
    const float* gamma      = (const float*)d_in[23];
    const float* gate_w     = (const float*)d_in[24];
    const float* gate_b     = (const float*)d_in[25];
    const float* fuse_w     = (const float*)d_in[26];
    const float* bn_g       = (const float*)d_in[27];
    const float* bn_b       = (const float*)d_in[28];

    float* arena = nullptr;
    hipGetSymbolAddress((void**)&arena, HIP_SYMBOL(g_arena));

    float* img_seq = arena;                    // 80000x128
    float* rad_seq = arena + 10240000;         // 80000x128
    float* score   = arena + 20480000;         // 80000
    int*   idx     = (int*)(arena + 20560000); // 40000 ints
    float* qh      = arena + 20480000;         // overlays score/idx (dead)
    float* xbuf    = arena + 20480000;         // overlays qh (dead after attn)
    float* kh      = arena + 30720000;         // 40000x128
    float* vh      = arena + 35840000;         // 40000x128
    float* fbuf    = arena + 40960000;         // kvn/qn/o/xn (<=40000x128)
    float* rad_e   = arena + 40960000;         // overlays fbuf (dead after FFN1); spans to 51.2M
    __hip_bfloat16* hbuf = (__hip_bfloat16*)arena; // 80000x512 bf16 over dead A+B

    // conv scratch (all over regions dead by the time they are written):
    u16* nhwc_hi = (u16*)arena;                   // 80000x384 bf16 hi  [0,15.36M) floats
    u16* nhwc_lo = (u16*)(arena + 20480000);      // 80000x384 bf16 lo  [20.48M,35.84M)
    u16* wgt_hi  = (u16*)(arena + 35840000);      // 384x9x384 bf16 hi  (over dead vh; NOT rad_e!)
    u16* wgt_lo  = wgt_hi + 1327104;              // 384x9x384 bf16 lo  (ends at 37.17M floats)

    const dim3 blk(256);

    // projections: NCHW -> seq [p][128]
    gemm128_kernel<float, float><<<dim3(1250, 1), blk, 0, stream>>>(
        image, img_proj_w, nullptr, nullptr, img_seq, 256, 128, 1, 0);
    gemm128_kernel<float, float><<<dim3(1250, 1), blk, 0, stream>>>(
        radar, rad_proj_w, nullptr, nullptr, rad_seq, 128, 128, 1, 0);

    // scoring MLP + top-k
    score_kernel<<<dim3(5000), blk, 0, stream>>>(
        rad_seq, img_seq, score_w1, score_b1, score_w2, score_b2, score);
    topk_kernel<<<dim3(400), blk, 0, stream>>>(score, idx);

    // gathered LN(kv) -> kvn (fbuf), then K/V projections
    ln_gather_kernel<<<dim3(20000), blk, 0, stream>>>(
        img_seq, idx, ln1kv_g, ln1kv_b, fbuf);
    gemm128_kernel<float, float><<<dim3(625, 1), blk, 0, stream>>>(
        fbuf, in_proj_w + 128 * 128, in_proj_b + 128, nullptr, kh, 128, 128, 0, 0);
    gemm128_kernel<float, float><<<dim3(625, 1), blk, 0, stream>>>(
        fbuf, in_proj_w + 256 * 128, in_proj_b + 256, nullptr, vh, 128, 128, 0, 0);

    // LN(q) -> qn (fbuf), Q projection -> qh
    ln_gather_kernel<<<dim3(40000), blk, 0, stream>>>(
        rad_seq, nullptr, ln1q_g, ln1q_b, fbuf);
    gemm128_kernel<float, float><<<dim3(1250, 1), blk, 0, stream>>>(
        fbuf, in_proj_w, in_proj_b, nullptr, qh, 128, 128, 0, 0);

    // attention -> o (fbuf)
    attention_kernel<<<dim3(8, 400), blk, 0, stream>>>(qh, kh, vh, fbuf);

    // out-proj + residual -> x
    gemm128_kernel<float, float><<<dim3(1250, 1), blk, 0, stream>>>(
        fbuf, out_proj_w, out_proj_b, rad_seq, xbuf, 128, 128, 0, 0);

    // FFN
    ln_gather_kernel<<<dim3(40000), blk, 0, stream>>>(
        xbuf, nullptr, ln2_g, ln2_b, fbuf);
    gemm128_kernel<float, __hip_bfloat16><<<dim3(1250, 4), blk, 0, stream>>>(
        fbuf, ffn_w1, ffn_b1, nullptr, hbuf, 128, 512, 0, 1);
    gemm128_kernel<__hip_bfloat16, float><<<dim3(1250, 1), blk, 0, stream>>>(
        hbuf, ffn_w2, ffn_b2, xbuf, xbuf, 512, 128, 0, 0);

    // enhance: rad_e = radar + gamma*gate*rmask*delta
    enhance_kernel<<<dim3(625, 2), blk, 0, stream>>>(
        xbuf, radar, image, rad_delta_w, gate_w, gate_b, gamma, rad_e);

    // conv prep: weight transpose+split (into dead vh region), input NHWC+split
    prep_weights_kernel<<<dim3(576), blk, 0, stream>>>(fuse_w, wgt_hi, wgt_lo);
    convert_nhwc_kernel<<<dim3(313), blk, 0, stream>>>(rad_e, image, nhwc_hi, nhwc_lo);

    // conv 3x3 (MFMA, split bf16) -> d_out; stats; batch-norm+relu in place
    conv_mfma_kernel<<<dim3(313, 2, 3), blk, 0, stream>>>(
        nhwc_hi, nhwc_lo, wgt_hi, wgt_lo, (float*)d_out);
    conv_stats_kernel<<<dim3(384), blk, 0, stream>>>((const float*)d_out);
    bn_relu_kernel<<<dim3(30000), blk, 0, stream>>>(
        (float*)d_out, bn_g, bn_b);
}

// Round 3
// 2121.716 us; speedup vs baseline: 6.9878x; 1.0525x over previous
//
#include <hip/hip_runtime.h>
#include <hip/hip_bf16.h>

#define EPSF 1e-5f

typedef unsigned short u16;
typedef __attribute__((ext_vector_type(8))) short short8v;   // 8 bf16 bits (4 VGPRs)
typedef __attribute__((ext_vector_type(4))) float f32x4;

// ---------------------------------------------------------------------------
// Module-scope scratch. 83.5M floats = 334 MB, lifetime-aliased.
// Map (float offsets):
//   [       0,15360000) nhwc0_hi  (bf16 [80000][384]: ch0-127 radar->enhanced, 128-383 image)
//   [15360000,30720000) nhwc0_lo  (live whole launch; ch0-127 rewritten by enhance_fuse)
//   [30720000,40960000) img_seq fp32               -+ later hbuf (bf16 80000x512 = 20.48M floats
//   [40960000,51200000) rad_seq fp32               -+  over both, after out-proj)
//   [51200000,61440000) score/idx -> qh -> xbuf (fp32 80000x128)
//   [61440000,66560000) kh fp32 40000x128           -+ later gatepre fp32 80000x128
//   [66560000,71680000) vh fp32 40000x128           -+  (over both, after attention)
//   [71680000,81920000) G: kvn/qn/o/xn split-bf16 planes -> delta fp32 80000x128
//   [81920000,82075648) WSEG: split weights (622592 u16)
//   [82100000,83427104) conv wgt hi/lo (2x1327104 u16)
// d_out written ONLY by conv + bn_relu. d_ws unused. d_in never written.
// Every region written before read within one launch (graph-replay idempotent).
// ---------------------------------------------------------------------------
__device__ float g_arena[83500000];
__device__ float g_stats[768];

// ---------------------------------------------------------------------------
// helpers
// ---------------------------------------------------------------------------
__device__ __forceinline__ float wave_sum(float v) {
#pragma unroll
    for (int o = 32; o > 0; o >>= 1) v += __shfl_down(v, o, 64);
    return v;
}

__device__ __forceinline__ float dot4(float4 a, float4 b) {
    return a.x * b.x + a.y * b.y + a.z * b.z + a.w * b.w;
}

// split fp32 -> bf16 hi + bf16 lo (lo = bf16(x - fp32(hi))); residual ~2^-17 rel
__device__ __forceinline__ void bf_split(float v, u16& h, u16& l) {
    __hip_bfloat16 bh = __float2bfloat16(v);
    float hv = __bfloat162float(bh);
    __hip_bfloat16 bl = __float2bfloat16(v - hv);
    h = *reinterpret_cast<u16*>(&bh);
    l = *reinterpret_cast<u16*>(&bl);
}

__device__ __forceinline__ void store_split4(u16* ph, u16* pl, float4 v) {
    u16 h0, l0, h1, l1, h2, l2, h3, l3;
    bf_split(v.x, h0, l0); bf_split(v.y, h1, l1);
    bf_split(v.z, h2, l2); bf_split(v.w, h3, l3);
    *(ushort4*)ph = make_ushort4(h0, h1, h2, h3);
    *(ushort4*)pl = make_ushort4(l0, l1, l2, l3);
}

// ---------------------------------------------------------------------------
// split_weights: all transformer/gemm weights -> WSEG split bf16 (hi|lo per seg)
// concatenated input index space, 311296 elems = 1216 blocks x 256
// ---------------------------------------------------------------------------
__global__ __launch_bounds__(256) void split_weights_kernel(
    const float* __restrict__ w_inproj, const float* __restrict__ w_outproj,
    const float* __restrict__ w_ffn1, const float* __restrict__ w_ffn2,
    const float* __restrict__ w_delta, const float* __restrict__ w_gate,
    const float* __restrict__ w_img, const float* __restrict__ w_rad,
    u16* __restrict__ wseg)
{
    int i = blockIdx.x * 256 + threadIdx.x;   // < 311296 exact
    const float* src; int local, base, numel;
    if (i < 49152)       { src = w_inproj;  local = i;          base = 0;      numel = 49152; }
    else if (i < 65536)  { src = w_outproj; local = i - 49152;  base = 98304;  numel = 16384; }
    else if (i < 131072) { src = w_ffn1;    local = i - 65536;  base = 131072; numel = 65536; }
    else if (i < 196608) { src = w_ffn2;    local = i - 131072; base = 262144; numel = 65536; }
    else if (i < 212992) { src = w_delta;   local = i - 196608; base = 393216; numel = 16384; }
    else if (i < 262144) { src = w_gate;    local = i - 212992; base = 425984; numel = 49152; }
    else if (i < 294912) { src = w_img;     local = i - 262144; base = 524288; numel = 32768; }
    else                 { src = w_rad;     local = i - 294912; base = 589824; numel = 16384; }
    u16 hh, ll;
    bf_split(src[local], hh, ll);
    wseg[base + local] = hh;
    wseg[base + numel + local] = ll;
}

// ---------------------------------------------------------------------------
// mfma_gemm: out[p][ocb+oc] = sum_k B[p][k] * W[ocb+oc][k]  (+bias,+resid,relu)
// Tile 128oc x 128pos, 4 waves 2x2, K-step 64, XOR chunk swizzle (verified in conv).
// A = weights pre-split bf16 (Ah,Al), row-major [Nout][K].
// BMODE: 0 = split bf16 planes (bh,bl, stride bstride)    -> 3 MFMA products
//        1 = single bf16 (bh)                             -> 2 products
//        2 = fp32 (bf), split on the fly in staging       -> 3 products
// OMODE: 0 = fp32 out; 1 = bf16 out
// ---------------------------------------------------------------------------
template <int BMODE, int OMODE, bool RELU>
__global__ __launch_bounds__(256, 2) void mfma_gemm_kernel(
    const u16* __restrict__ Ah, const u16* __restrict__ Al,
    const u16* __restrict__ bh, const u16* __restrict__ bl,
    const float* __restrict__ bf, int bstride,
    const float* __restrict__ bias, const float* __restrict__ resid,
    float* __restrict__ outf, u16* __restrict__ outh,
    int K, int Nout, int P)
{
    __shared__ alignas(16) u16 sAh[8192], sAl[8192], sBh[8192], sBl[8192];

    const int tid  = threadIdx.x;
    const int lane = tid & 63;
    const int wid  = tid >> 6;
    const int wrm  = wid >> 1;
    const int wcn  = wid & 1;
    const int p0   = blockIdx.x * 128;
    const int ocb  = blockIdx.y * 128;

    const int r0  = tid >> 3;
    const int cl  = tid & 7;
    const int swz = cl ^ (r0 & 7);

    f32x4 acc[4][4];
#pragma unroll
    for (int i = 0; i < 4; ++i)
#pragma unroll
        for (int j = 0; j < 4; ++j) acc[i][j] = (f32x4){0.f, 0.f, 0.f, 0.f};

    const int fr = lane & 15;
    const int fc = lane >> 4;

    for (int kk = 0; kk < K; kk += 64) {
        __syncthreads();
#pragma unroll
        for (int k = 0; k < 4; ++k) {
            int row = r0 + k * 32;
            int di = row * 64 + swz * 8;
            size_t ga = (size_t)(ocb + row) * K + kk + cl * 8;
            *(short8v*)&sAh[di] = *(const short8v*)&Ah[ga];
            *(short8v*)&sAl[di] = *(const short8v*)&Al[ga];
            int p = p0 + row;
            if (BMODE == 0) {
                if (p < P) {
                    size_t gb = (size_t)p * bstride + kk + cl * 8;
                    *(short8v*)&sBh[di] = *(const short8v*)&bh[gb];
                    *(short8v*)&sBl[di] = *(const short8v*)&bl[gb];
                } else {
                    short8v z = {0,0,0,0,0,0,0,0};
                    *(short8v*)&sBh[di] = z;
                    *(short8v*)&sBl[di] = z;
                }
            } else if (BMODE == 1) {
                if (p < P) {
                    size_t gb = (size_t)p * bstride + kk + cl * 8;
                    *(short8v*)&sBh[di] = *(const short8v*)&bh[gb];
                } else {
                    short8v z = {0,0,0,0,0,0,0,0};
                    *(short8v*)&sBh[di] = z;
                }
            } else {
                short8v vh8 = {0,0,0,0,0,0,0,0}, vl8 = {0,0,0,0,0,0,0,0};
                if (p < P) {
                    const float* src = bf + (size_t)p * bstride + kk + cl * 8;
                    float4 f0 = *(const float4*)(src);
                    float4 f1 = *(const float4*)(src + 4);
                    float fv[8] = {f0.x, f0.y, f0.z, f0.w, f1.x, f1.y, f1.z, f1.w};
#pragma unroll
                    for (int j = 0; j < 8; ++j) {
                        u16 hh, ll;
                        bf_split(fv[j], hh, ll);
                        vh8[j] = (short)hh;
                        vl8[j] = (short)ll;
                    }
                }
                *(short8v*)&sBh[di] = vh8;
                *(short8v*)&sBl[di] = vl8;
            }
        }
        __syncthreads();
#pragma unroll
        for (int h = 0; h < 2; ++h) {
            const int kc = h * 4 + fc;
            short8v bhf[4], blf[4];
#pragma unroll
            for (int nn = 0; nn < 4; ++nn) {
                int row = wcn * 64 + nn * 16 + fr;
                int idx = row * 64 + ((kc ^ (row & 7)) << 3);
                bhf[nn] = *(const short8v*)&sBh[idx];
                if (BMODE != 1) blf[nn] = *(const short8v*)&sBl[idx];
            }
#pragma unroll
            for (int mm = 0; mm < 4; ++mm) {
                int row = wrm * 64 + mm * 16 + fr;
                int idx = row * 64 + ((kc ^ (row & 7)) << 3);
                short8v ahf = *(const short8v*)&sAh[idx];
                short8v alf = *(const short8v*)&sAl[idx];
#pragma unroll
                for (int nn = 0; nn < 4; ++nn)
                    acc[mm][nn] = __builtin_amdgcn_mfma_f32_16x16x32_bf16(
                        ahf, bhf[nn], acc[mm][nn], 0, 0, 0);
                if (BMODE != 1) {
#pragma unroll
                    for (int nn = 0; nn < 4; ++nn)
                        acc[mm][nn] = __builtin_amdgcn_mfma_f32_16x16x32_bf16(
                            ahf, blf[nn], acc[mm][nn], 0, 0, 0);
                }
#pragma unroll
                for (int nn = 0; nn < 4; ++nn)
                    acc[mm][nn] = __builtin_amdgcn_mfma_f32_16x16x32_bf16(
                        alf, bhf[nn], acc[mm][nn], 0, 0, 0);
            }
        }
    }

    // epilogue: D[row=oc][col=pos] -> out[p][oc], 4 regs = 4 consecutive oc
#pragma unroll
    for (int mm = 0; mm < 4; ++mm) {
        int base = ocb + wrm * 64 + mm * 16 + fc * 4;
        float4 bv = {0.f, 0.f, 0.f, 0.f};
        if (bias) bv = *(const float4*)&bias[base];
#pragma unroll
        for (int nn = 0; nn < 4; ++nn) {
            int p = p0 + wcn * 64 + nn * 16 + fr;
            if (p < P) {
                size_t row = (size_t)p * Nout + base;
                float4 r;
                r.x = acc[mm][nn][0] + bv.x;
                r.y = acc[mm][nn][1] + bv.y;
                r.z = acc[mm][nn][2] + bv.z;
                r.w = acc[mm][nn][3] + bv.w;
                if (resid) {
                    float4 rr = *(const float4*)&resid[row];
                    r.x += rr.x; r.y += rr.y; r.z += rr.z; r.w += rr.w;
                }
                if (RELU) {
                    r.x = fmaxf(r.x, 0.f); r.y = fmaxf(r.y, 0.f);
                    r.z = fmaxf(r.z, 0.f); r.w = fmaxf(r.w, 0.f);
                }
                if (OMODE == 0) {
                    *(float4*)&outf[row] = r;
                } else {
                    __hip_bfloat16 b0 = __float2bfloat16(r.x);
                    __hip_bfloat16 b1 = __float2bfloat16(r.y);
                    __hip_bfloat16 b2 = __float2bfloat16(r.z);
                    __hip_bfloat16 b3 = __float2bfloat16(r.w);
                    *(ushort4*)&outh[row] = make_ushort4(
                        *reinterpret_cast<u16*>(&b0), *reinterpret_cast<u16*>(&b1),
                        *reinterpret_cast<u16*>(&b2), *reinterpret_cast<u16*>(&b3));
                }
            }
        }
    }
}

// ---------------------------------------------------------------------------
// score: h = relu(si @ W1^T + b1) (64), score = h @ w2 + b2
// ---------------------------------------------------------------------------
__global__ __launch_bounds__(256) void score_kernel(
    const float* __restrict__ rad_seq, const float* __restrict__ img_seq,
    const float* __restrict__ w1, const float* __restrict__ b1,
    const float* __restrict__ w2, const float* __restrict__ b2,
    float* __restrict__ score)
{
    __shared__ float sw1[64][20];
    __shared__ float ss[16][20];
    const int tid = threadIdx.x;
    const int p0 = blockIdx.x * 16;
    const int wvid = tid >> 6;
    const int l = tid & 63;
    float acc[4] = {0.f, 0.f, 0.f, 0.f};

    for (int cb = 0; cb < 256; cb += 16) {
        __syncthreads();
#pragma unroll
        for (int i = 0; i < 4; i++) {
            int e = tid + i * 256;
            int ll = e >> 4, cc = e & 15;
            sw1[ll][cc] = w1[(size_t)ll * 256 + cb + cc];
        }
        {
            int pos = tid >> 4, cc = tid & 15;
            int c = cb + cc;
            ss[pos][cc] = (c < 128)
                ? rad_seq[(size_t)(p0 + pos) * 128 + c]
                : img_seq[(size_t)(p0 + pos) * 128 + (c - 128)];
        }
        __syncthreads();
#pragma unroll
        for (int c4 = 0; c4 < 4; c4++) {
            float4 wv = *(const float4*)&sw1[l][c4 * 4];
#pragma unroll
            for (int j = 0; j < 4; j++) {
                float4 sv = *(const float4*)&ss[wvid * 4 + j][c4 * 4];
                acc[j] += dot4(wv, sv);
            }
        }
    }
    float b1v = b1[l], w2v = w2[l], b2v = b2[0];
#pragma unroll
    for (int j = 0; j < 4; j++) {
        float h = fmaxf(acc[j] + b1v, 0.f);
        float v = wave_sum(h * w2v);
        if (l == 0) score[p0 + wvid * 4 + j] = v + b2v;
    }
}

// ---------------------------------------------------------------------------
// topk: exact stable rank selection (matches jax.lax.top_k tie-breaking)
// ---------------------------------------------------------------------------
__global__ __launch_bounds__(256) void topk_kernel(
    const float* __restrict__ score, int* __restrict__ idx)
{
    __shared__ float s[200];
    const int n = blockIdx.x;
    const int t = threadIdx.x;
    if (t < 200) s[t] = score[(size_t)n * 200 + t];
    __syncthreads();
    if (t < 200) {
        float my = s[t];
        int cnt = 0;
        for (int j = 0; j < 200; j++) {
            float o = s[j];
            cnt += (o > my) || (o == my && j < t);
        }
        if (cnt < 100) idx[n * 100 + cnt] = t;
    }
}

// ---------------------------------------------------------------------------
// ln_gather: out[r][:] = LN(in[src_row][:]) * g + b  -> split bf16 planes
// ---------------------------------------------------------------------------
__global__ __launch_bounds__(256) void ln_gather_kernel(
    const float* __restrict__ in, const int* __restrict__ gidx,
    const float* __restrict__ g, const float* __restrict__ bb,
    u16* __restrict__ oh, u16* __restrict__ ol)
{
    __shared__ float red[4];
    const int tid = threadIdx.x;
    const int grp = tid >> 7;
    const int t = tid & 127;
    const int r = blockIdx.x * 2 + grp;

    size_t src_row;
    if (gidx) src_row = (size_t)(r / 100) * 200 + gidx[r];
    else      src_row = (size_t)r;

    float x = in[src_row * 128 + t];
    float s = wave_sum(x);
    if ((tid & 63) == 0) red[tid >> 6] = s;
    __syncthreads();
    float m = (red[grp * 2] + red[grp * 2 + 1]) * 0.0078125f;
    float d = x - m;
    float s2 = wave_sum(d * d);
    __syncthreads();
    if ((tid & 63) == 0) red[tid >> 6] = s2;
    __syncthreads();
    float var = (red[grp * 2] + red[grp * 2 + 1]) * 0.0078125f;
    float y = d * rsqrtf(var + EPSF) * g[t] + bb[t];
    u16 hh, ll;
    bf_split(y, hh, ll);
    oh[(size_t)r * 128 + t] = hh;
    ol[(size_t)r * 128 + t] = ll;
}

// ---------------------------------------------------------------------------
// attention: block = (head h, row n); thread = one query w (<200)
// outputs split bf16 planes
// ---------------------------------------------------------------------------
__global__ __launch_bounds__(256) void attention_kernel(
    const float* __restrict__ qh, const float* __restrict__ kh,
    const float* __restrict__ vh, u16* __restrict__ o_hi, u16* __restrict__ o_lo)
{
    __shared__ float sk[100][16];
    __shared__ float sv[100][16];
    const int h = blockIdx.x;
    const int n = blockIdx.y;
    const int tid = threadIdx.x;

    for (int e = tid; e < 1600; e += 256) {
        int kk = e >> 4, d = e & 15;
        size_t src = ((size_t)n * 100 + kk) * 128 + h * 16 + d;
        sk[kk][d] = kh[src];
        sv[kk][d] = vh[src];
    }
    __syncthreads();

    if (tid < 200) {
        const float* qp = &qh[((size_t)n * 200 + tid) * 128 + h * 16];
        float4 q0 = *(const float4*)(qp + 0);
        float4 q1 = *(const float4*)(qp + 4);
        float4 q2 = *(const float4*)(qp + 8);
        float4 q3 = *(const float4*)(qp + 12);

        float m = -INFINITY, l = 0.f;
        float4 a0 = {0,0,0,0}, a1 = {0,0,0,0}, a2 = {0,0,0,0}, a3 = {0,0,0,0};

        for (int kk = 0; kk < 100; kk++) {
            const float4* kp = (const float4*)&sk[kk][0];
            float s = dot4(q0, kp[0]) + dot4(q1, kp[1]) +
                      dot4(q2, kp[2]) + dot4(q3, kp[3]);
            s *= 0.25f;
            float nm = fmaxf(m, s);
            float corr = __expf(m - nm);
            float pe = __expf(s - nm);
            l = l * corr + pe;
            const float4* vp = (const float4*)&sv[kk][0];
            float4 v0 = vp[0], v1 = vp[1], v2 = vp[2], v3 = vp[3];
            a0.x = a0.x * corr + pe * v0.x; a0.y = a0.y * corr + pe * v0.y;
            a0.z = a0.z * corr + pe * v0.z; a0.w = a0.w * corr + pe * v0.w;
            a1.x = a1.x * corr + pe * v1.x; a1.y = a1.y * corr + pe * v1.y;
            a1.z = a1.z * corr + pe * v1.z; a1.w = a1.w * corr + pe * v1.w;
            a2.x = a2.x * corr + pe * v2.x; a2.y = a2.y * corr + pe * v2.y;
            a2.z = a2.z * corr + pe * v2.z; a2.w = a2.w * corr + pe * v2.w;
            a3.x = a3.x * corr + pe * v3.x; a3.y = a3.y * corr + pe * v3.y;
            a3.z = a3.z * corr + pe * v3.z; a3.w = a3.w * corr + pe * v3.w;
            m = nm;
        }
        float inv = 1.f / l;
        a0.x *= inv; a0.y *= inv; a0.z *= inv; a0.w *= inv;
        a1.x *= inv; a1.y *= inv; a1.z *= inv; a1.w *= inv;
        a2.x *= inv; a2.y *= inv; a2.z *= inv; a2.w *= inv;
        a3.x *= inv; a3.y *= inv; a3.z *= inv; a3.w *= inv;
        size_t ob = ((size_t)n * 200 + tid) * 128 + h * 16;
        store_split4(&o_hi[ob + 0],  &o_lo[ob + 0],  a0);
        store_split4(&o_hi[ob + 4],  &o_lo[ob + 4],  a1);
        store_split4(&o_hi[ob + 8],  &o_lo[ob + 8],  a2);
        store_split4(&o_hi[ob + 12], &o_lo[ob + 12], a3);
    }
}

// ---------------------------------------------------------------------------
// prep_weights: fuse_w [oc][ic][ky][kx] fp32 -> conv wgt hi/lo [oc][s][ic] bf16
// ---------------------------------------------------------------------------
__global__ __launch_bounds__(256) void prep_weights_kernel(
    const float* __restrict__ fw, u16* __restrict__ wh, u16* __restrict__ wl)
{
    int idx = blockIdx.x * 256 + threadIdx.x;   // < 384*384 = 147456
    int oc = idx / 384;
    int ic = idx - oc * 384;
    const float* src = fw + (size_t)idx * 9;
    u16* dh = wh + (size_t)oc * 3456 + ic;
    u16* dl = wl + (size_t)oc * 3456 + ic;
#pragma unroll
    for (int s = 0; s < 9; ++s) {
        u16 hh, ll;
        bf_split(src[s], hh, ll);
        dh[(size_t)s * 384] = hh;
        dl[(size_t)s * 384] = ll;
    }
}

// ---------------------------------------------------------------------------
// convert_nhwc: concat(radar[0:128], image[0:256]) NCHW fp32 -> NHWC bf16 split
// ---------------------------------------------------------------------------
__global__ __launch_bounds__(256) void convert_nhwc_kernel(
    const float* __restrict__ radar, const float* __restrict__ image,
    u16* __restrict__ oh, u16* __restrict__ ol)
{
    int p = blockIdx.x * 256 + threadIdx.x;
    if (p >= 80000) return;
    int b = p >= 40000 ? 1 : 0;
    int hw = p - b * 40000;
    u16* ph = oh + (size_t)p * 384;
    u16* pl = ol + (size_t)p * 384;
#pragma unroll 1
    for (int g = 0; g < 48; ++g) {
        short8v vh, vl;
#pragma unroll
        for (int j = 0; j < 8; ++j) {
            int c = g * 8 + j;
            float v = (c < 128)
                ? radar[((size_t)(b * 128 + c)) * 40000 + hw]
                : image[((size_t)(b * 256 + (c - 128))) * 40000 + hw];
            u16 hh, ll;
            bf_split(v, hh, ll);
            vh[j] = (short)hh;
            vl[j] = (short)ll;
        }
        *(short8v*)&ph[g * 8] = vh;
        *(short8v*)&pl[g * 8] = vl;
    }
}

// ---------------------------------------------------------------------------
// enhance_fuse: nhwc0[p][0:128] = split(radar + gamma*sigmoid(gatepre)*rmask*delta)
// (only radar channels rewritten; image channels 128-383 untouched)
// ---------------------------------------------------------------------------
__global__ __launch_bounds__(256) void enhance_fuse_kernel(
    const float* __restrict__ delta, const float* __restrict__ gatepre,
    const float* __restrict__ radar, const float* __restrict__ gamma_p,
    u16* __restrict__ nh, u16* __restrict__ nl)
{
    __shared__ float srad[64][136];   // [pos][oc], padded
    const int tid = threadIdx.x;
    const int blk = blockIdx.x;        // 0..1249 (625 per b)
    const int b = blk >= 625 ? 1 : 0;
    const int hw0 = (blk - b * 625) * 64;
    const int p0 = b * 40000 + hw0;

#pragma unroll
    for (int i = 0; i < 32; ++i) {
        int e = tid + i * 256;         // 8192 elems
        int oc = e >> 6, pos = e & 63;
        srad[pos][oc] = radar[((size_t)(b * 128 + oc)) * 40000 + hw0 + pos];
    }
    __syncthreads();

    const float gmm = gamma_p[0];
    const int c4 = tid & 31;           // oc quad index
    const int rr = tid >> 5;           // 0..7
#pragma unroll
    for (int j = 0; j < 8; ++j) {
        int pos = j * 8 + rr;
        int p = p0 + pos;
        int hw = hw0 + pos;
        int hrow = hw / 200;
        float rm = fmaxf(0.3f, 1.0f - 0.7f * ((float)hrow * (1.0f / 199.0f)));
        float4 dv = *(const float4*)&delta[(size_t)p * 128 + c4 * 4];
        float4 gv = *(const float4*)&gatepre[(size_t)p * 128 + c4 * 4];
        float4 rv = *(const float4*)&srad[pos][c4 * 4];
        float4 r;
        r.x = rv.x + gmm * (1.f / (1.f + __expf(-gv.x))) * rm * dv.x;
        r.y = rv.y + gmm * (1.f / (1.f + __expf(-gv.y))) * rm * dv.y;
        r.z = rv.z + gmm * (1.f / (1.f + __expf(-gv.z))) * rm * dv.z;
        r.w = rv.w + gmm * (1.f / (1.f + __expf(-gv.w))) * rm * dv.w;
        store_split4(&nh[(size_t)p * 384 + c4 * 4], &nl[(size_t)p * 384 + c4 * 4], r);
    }
}

// ---------------------------------------------------------------------------
// conv_mfma: 3x3 SAME conv as 9 shifted GEMMs on matrix cores (unchanged, R2-verified)
// ---------------------------------------------------------------------------
__global__ __launch_bounds__(256, 2) void conv_mfma_kernel(
    const u16* __restrict__ nhwc_hi, const u16* __restrict__ nhwc_lo,
    const u16* __restrict__ wgt_hi,  const u16* __restrict__ wgt_lo,
    float* __restrict__ out)
{
    __shared__ alignas(16) u16 sAh[8192], sAl[8192], sBh[8192], sBl[8192];

    const int tid  = threadIdx.x;
    const int lane = tid & 63;
    const int wid  = tid >> 6;
    const int wrm  = wid >> 1;
    const int wcn  = wid & 1;
    const int hw0  = blockIdx.x * 128;
    const int b    = blockIdx.y;
    const int oc0  = blockIdx.z * 128;

    const int r0  = tid >> 3;
    const int cl  = tid & 7;
    const int swz = cl ^ (r0 & 7);

    const int y0 = hw0 / 200;
    const int x0 = hw0 - y0 * 200;

    f32x4 acc[4][4];
#pragma unroll
    for (int i = 0; i < 4; ++i)
#pragma unroll
        for (int j = 0; j < 4; ++j) acc[i][j] = (f32x4){0.f, 0.f, 0.f, 0.f};

    size_t abase[4];
#pragma unroll
    for (int k = 0; k < 4; ++k)
        abase[k] = (size_t)(oc0 + r0 + k * 32) * 3456 + cl * 8;

    const int fr = lane & 15;
    const int fc = lane >> 4;

    for (int s = 0; s < 9; ++s) {
        const int dy = s / 3 - 1;
        const int dx = s % 3 - 1;
        size_t bsrc[4];
        int bval[4];
#pragma unroll
        for (int k = 0; k < 4; ++k) {
            int row = r0 + k * 32;
            int hwo = hw0 + row;
            int xr  = x0 + row;
            int wrp = (xr >= 200) ? 1 : 0;
            int yy  = y0 + wrp + dy;
            int xx  = xr - wrp * 200 + dx;
            int v = (hwo < 40000) && ((unsigned)yy < 200u) && ((unsigned)xx < 200u);
            bval[k] = v;
            bsrc[k] = v ? ((size_t)(b * 40000 + yy * 200 + xx) * 384 + cl * 8) : 0;
        }
        const size_t wofs = (size_t)s * 384;

        for (int icb = 0; icb < 6; ++icb) {
            const int ic0 = icb * 64;
            __syncthreads();
#pragma unroll
            for (int k = 0; k < 4; ++k) {
                int di = (r0 + k * 32) * 64 + swz * 8;
                size_t ga = abase[k] + wofs + ic0;
                *(short8v*)&sAh[di] = *(const short8v*)&wgt_hi[ga];
                *(short8v*)&sAl[di] = *(const short8v*)&wgt_lo[ga];
                if (bval[k]) {
                    size_t gb = bsrc[k] + ic0;
                    *(short8v*)&sBh[di] = *(const short8v*)&nhwc_hi[gb];
                    *(short8v*)&sBl[di] = *(const short8v*)&nhwc_lo[gb];
                } else {
                    short8v z = {0, 0, 0, 0, 0, 0, 0, 0};
                    *(short8v*)&sBh[di] = z;
                    *(short8v*)&sBl[di] = z;
                }
            }
            __syncthreads();
#pragma unroll
            for (int h = 0; h < 2; ++h) {
                const int kc = h * 4 + fc;
                short8v bhf[4], blf[4];
#pragma unroll
                for (int nn = 0; nn < 4; ++nn) {
                    int row = wcn * 64 + nn * 16 + fr;
                    int idx = row * 64 + ((kc ^ (row & 7)) << 3);
                    bhf[nn] = *(const short8v*)&sBh[idx];
                    blf[nn] = *(const short8v*)&sBl[idx];
                }
#pragma unroll
                for (int mm = 0; mm < 4; ++mm) {
                    int row = wrm * 64 + mm * 16 + fr;
                    int idx = row * 64 + ((kc ^ (row & 7)) << 3);
                    short8v ahf = *(const short8v*)&sAh[idx];
                    short8v alf = *(const short8v*)&sAl[idx];
#pragma unroll
                    for (int nn = 0; nn < 4; ++nn)
                        acc[mm][nn] = __builtin_amdgcn_mfma_f32_16x16x32_bf16(
                            ahf, bhf[nn], acc[mm][nn], 0, 0, 0);
#pragma unroll
                    for (int nn = 0; nn < 4; ++nn)
                        acc[mm][nn] = __builtin_amdgcn_mfma_f32_16x16x32_bf16(
                            ahf, blf[nn], acc[mm][nn], 0, 0, 0);
#pragma unroll
                    for (int nn = 0; nn < 4; ++nn)
                        acc[mm][nn] = __builtin_amdgcn_mfma_f32_16x16x32_bf16(
                            alf, bhf[nn], acc[mm][nn], 0, 0, 0);
                }
            }
        }
    }

#pragma unroll
    for (int mm = 0; mm < 4; ++mm) {
        int oc = oc0 + wrm * 64 + mm * 16 + fc * 4;
#pragma unroll
        for (int nn = 0; nn < 4; ++nn) {
            int p = hw0 + wcn * 64 + nn * 16 + fr;
            if (p < 40000) {
                float* op = out + (size_t)(b * 384 + oc) * 40000 + p;
#pragma unroll
                for (int r = 0; r < 4; ++r)
                    op[(size_t)r * 40000] = acc[mm][nn][r];
            }
        }
    }
}

// ---------------------------------------------------------------------------
// conv_stats: per-channel sum / sumsq over (B,H,W) -> g_stats (no atomics)
// ---------------------------------------------------------------------------
__global__ __launch_bounds__(256) void conv_stats_kernel(const float* __restrict__ out)
{
    const int c = blockIdx.x;           // 0..383
    float s1 = 0.f, s2 = 0.f;
#pragma unroll
    for (int b = 0; b < 2; ++b) {
        const float4* pp = (const float4*)(out + (size_t)(b * 384 + c) * 40000);
        for (int i = threadIdx.x; i < 10000; i += 256) {
            float4 v = pp[i];
            s1 += v.x + v.y + v.z + v.w;
            s2 += v.x * v.x + v.y * v.y + v.z * v.z + v.w * v.w;
        }
    }
    s1 = wave_sum(s1);
    s2 = wave_sum(s2);
    __shared__ float r1[4], r2[4];
    if ((threadIdx.x & 63) == 0) {
        r1[threadIdx.x >> 6] = s1;
        r2[threadIdx.x >> 6] = s2;
    }
    __syncthreads();
    if (threadIdx.x == 0) {
        g_stats[c * 2]     = r1[0] + r1[1] + r1[2] + r1[3];
        g_stats[c * 2 + 1] = r2[0] + r2[1] + r2[2] + r2[3];
    }
}

// ---------------------------------------------------------------------------
// bn_relu: in-place on d_out
// ---------------------------------------------------------------------------
__global__ __launch_bounds__(256) void bn_relu_kernel(
    float* __restrict__ out, const float* __restrict__ g,
    const float* __restrict__ bb)
{
    int i = blockIdx.x * 256 + threadIdx.x;   // float4 index < 7,680,000
    int flat = i * 4;
    int oc = (flat / 40000) % 384;
    float m = g_stats[oc * 2] * (1.f / 80000.f);
    float v = g_stats[oc * 2 + 1] * (1.f / 80000.f) - m * m;
    float inv = rsqrtf(v + EPSF);
    float sc = g[oc] * inv;
    float sh = bb[oc] - m * sc;
    float4 c = ((float4*)out)[i];
    c.x = fmaxf(c.x * sc + sh, 0.f);
    c.y = fmaxf(c.y * sc + sh, 0.f);
    c.z = fmaxf(c.z * sc + sh, 0.f);
    c.w = fmaxf(c.w * sc + sh, 0.f);
    ((float4*)out)[i] = c;
}

// ---------------------------------------------------------------------------
// launch
// ---------------------------------------------------------------------------
extern "C" void kernel_launch(void* const* d_in, const int* in_sizes, int n_in,
                              void* d_out, int out_size, void* d_ws, size_t ws_size,
                              hipStream_t stream)
{
    (void)in_sizes; (void)n_in; (void)out_size; (void)d_ws; (void)ws_size;

    const float* radar      = (const float*)d_in[0];
    const float* image      = (const float*)d_in[1];
    const float* img_proj_w = (const float*)d_in[2];
    const float* rad_proj_w = (const float*)d_in[3];
    const float* in_proj_w  = (const float*)d_in[4];
    const float* in_proj_b  = (const float*)d_in[5];
    const float* out_proj_w = (const float*)d_in[6];
    const float* out_proj_b = (const float*)d_in[7];
    const float* ln1q_g     = (const float*)d_in[8];
    const float* ln1q_b     = (const float*)d_in[9];
    const float* ln1kv_g    = (const float*)d_in[10];
    const float* ln1kv_b    = (const float*)d_in[11];
    const float* ln2_g      = (const float*)d_in[12];
    const float* ln2_b      = (const float*)d_in[13];
    const float* ffn_w1     = (const float*)d_in[14];
    const float* ffn_b1     = (const float*)d_in[15];
    const float* ffn_w2     = (const float*)d_in[16];
    const float* ffn_b2     = (const float*)d_in[17];
    const float* score_w1   = (const float*)d_in[18];
    const float* score_b1   = (const float*)d_in[19];
    const float* score_w2   = (const float*)d_in[20];
    const float* score_b2   = (const float*)d_in[21];
    const float* rad_delta_w= (const float*)d_in[22];
    const float* gamma      = (const float*)d_in[23];
    const float* gate_w     = (const float*)d_in[24];
    const float* gate_b     = (const float*)d_in[25];
    const float* fuse_w     = (const float*)d_in[26];
    const float* bn_g       = (const float*)d_in[27];
    const float* bn_b       = (const float*)d_in[28];

    float* arena = nullptr;
    hipGetSymbolAddress((void**)&arena, HIP_SYMBOL(g_arena));

    // --- arena regions (see map above) ---
    u16*   nh_hi   = (u16*)arena;                       // [80000][384] hi
    u16*   nh_lo   = (u16*)(arena + 15360000);          // [80000][384] lo
    float* img_seq = arena + 30720000;                  // [80000][128] fp32
    float* rad_seq = arena + 40960000;                  // [80000][128] fp32
    float* score   = arena + 51200000;                  // 80000 f
    int*   idx     = (int*)(arena + 51280000);          // 40000 int
    float* qh      = arena + 51200000;                  // overlays score/idx
    float* xbuf    = arena + 51200000;                  // overlays qh
    float* kh      = arena + 61440000;                  // [40000][128]
    float* vh      = arena + 66560000;                  // [40000][128]
    float* gatepre = arena + 61440000;                  // [80000][128] over kh+vh
    u16*   gbase   = (u16*)(arena + 71680000);          // split-plane region G
    u16*   kvn_hi  = gbase,              *kvn_lo = gbase + 5120000;   // [40000][128]
    u16*   qn_hi   = gbase,              *qn_lo  = gbase + 10240000;  // [80000][128]
    u16*   o_hi    = gbase,              *o_lo   = gbase + 10240000;  // [80000][128]
    u16*   xn_hi   = gbase,              *xn_lo  = gbase + 10240000;  // [80000][128]
    float* delta   = arena + 71680000;                  // [80000][128] over G
    u16*   hbuf    = (u16*)(arena + 30720000);          // [80000][512] bf16 over img+rad_seq
    u16*   wseg    = (u16*)(arena + 81920000);          // split weights
    u16*   cwgt_hi = (u16*)(arena + 82100000);          // conv wgt
    u16*   cwgt_lo = cwgt_hi + 1327104;

    // split-weight sub-pointers (u16 offsets within wseg)
    const u16* w_q_hi    = wseg + 0,      *w_q_lo    = wseg + 49152;          // in_proj rows 0-127
    const u16* w_k_hi    = wseg + 16384,  *w_k_lo    = wseg + 49152 + 16384;  // rows 128-255
    const u16* w_v_hi    = wseg + 32768,  *w_v_lo    = wseg + 49152 + 32768;  // rows 256-383
    const u16* w_out_hi  = wseg + 98304,  *w_out_lo  = wseg + 114688;
    const u16* w_ffn1_hi = wseg + 131072, *w_ffn1_lo = wseg + 196608;
    const u16* w_ffn2_hi = wseg + 262144, *w_ffn2_lo = wseg + 327680;
    const u16* w_dlt_hi  = wseg + 393216, *w_dlt_lo  = wseg + 409600;
    const u16* w_gate_hi = wseg + 425984, *w_gate_lo = wseg + 475136;
    const u16* w_img_hi  = wseg + 524288, *w_img_lo  = wseg + 557056;
    const u16* w_rad_hi  = wseg + 589824, *w_rad_lo  = wseg + 606208;

    const dim3 blk(256);

    // prep: weight splits + NHWC conversion of (radar|image)
    split_weights_kernel<<<dim3(1216), blk, 0, stream>>>(
        in_proj_w, out_proj_w, ffn_w1, ffn_w2, rad_delta_w, gate_w,
        img_proj_w, rad_proj_w, wseg);
    prep_weights_kernel<<<dim3(576), blk, 0, stream>>>(fuse_w, cwgt_hi, cwgt_lo);
    convert_nhwc_kernel<<<dim3(313), blk, 0, stream>>>(radar, image, nh_hi, nh_lo);

    // projections: NHWC bf16 -> seq fp32
    mfma_gemm_kernel<0, 0, false><<<dim3(625, 1), blk, 0, stream>>>(
        w_rad_hi, w_rad_lo, nh_hi, nh_lo, nullptr, 384,
        nullptr, nullptr, rad_seq, nullptr, 128, 128, 80000);
    mfma_gemm_kernel<0, 0, false><<<dim3(625, 1), blk, 0, stream>>>(
        w_img_hi, w_img_lo, nh_hi + 128, nh_lo + 128, nullptr, 384,
        nullptr, nullptr, img_seq, nullptr, 256, 128, 80000);

    // scoring MLP + top-k
    score_kernel<<<dim3(5000), blk, 0, stream>>>(
        rad_seq, img_seq, score_w1, score_b1, score_w2, score_b2, score);
    topk_kernel<<<dim3(400), blk, 0, stream>>>(score, idx);

    // gathered LN(kv) -> kvn planes, K/V projections
    ln_gather_kernel<<<dim3(20000), blk, 0, stream>>>(
        img_seq, idx, ln1kv_g, ln1kv_b, kvn_hi, kvn_lo);
    mfma_gemm_kernel<0, 0, false><<<dim3(313, 1), blk, 0, stream>>>(
        w_k_hi, w_k_lo, kvn_hi, kvn_lo, nullptr, 128,
        in_proj_b + 128, nullptr, kh, nullptr, 128, 128, 40000);
    mfma_gemm_kernel<0, 0, false><<<dim3(313, 1), blk, 0, stream>>>(
        w_v_hi, w_v_lo, kvn_hi, kvn_lo, nullptr, 128,
        in_proj_b + 256, nullptr, vh, nullptr, 128, 128, 40000);

    // LN(q) -> qn planes (over dead kvn), Q projection -> qh (over dead score/idx)
    ln_gather_kernel<<<dim3(40000), blk, 0, stream>>>(
        rad_seq, nullptr, ln1q_g, ln1q_b, qn_hi, qn_lo);
    mfma_gemm_kernel<0, 0, false><<<dim3(625, 1), blk, 0, stream>>>(
        w_q_hi, w_q_lo, qn_hi, qn_lo, nullptr, 128,
        in_proj_b, nullptr, qh, nullptr, 128, 128, 80000);

    // attention -> o planes (over dead qn)
    attention_kernel<<<dim3(8, 400), blk, 0, stream>>>(qh, kh, vh, o_hi, o_lo);

    // out-proj + residual -> xbuf (over dead qh)
    mfma_gemm_kernel<0, 0, false><<<dim3(625, 1), blk, 0, stream>>>(
        w_out_hi, w_out_lo, o_hi, o_lo, nullptr, 128,
        out_proj_b, rad_seq, xbuf, nullptr, 128, 128, 80000);

    // FFN: ln2 -> xn planes (over dead o); FFN1 -> hbuf bf16 (over dead seqs);
    // FFN2 -> xbuf in place
    ln_gather_kernel<<<dim3(40000), blk, 0, stream>>>(
        xbuf, nullptr, ln2_g, ln2_b, xn_hi, xn_lo);
    mfma_gemm_kernel<0, 1, true><<<dim3(625, 4), blk, 0, stream>>>(
        w_ffn1_hi, w_ffn1_lo, xn_hi, xn_lo, nullptr, 128,
        ffn_b1, nullptr, nullptr, hbuf, 128, 512, 80000);
    mfma_gemm_kernel<1, 0, false><<<dim3(625, 1), blk, 0, stream>>>(
        w_ffn2_hi, w_ffn2_lo, hbuf, nullptr, nullptr, 512,
        ffn_b2, xbuf, xbuf, nullptr, 512, 128, 80000);

    // enhance: delta gemm (fp32 B, over dead xn) + gate gemm (over dead kh/vh)
    // + fused sigmoid/rmask/residual writing nhwc0 radar channels
    mfma_gemm_kernel<2, 0, false><<<dim3(625, 1), blk, 0, stream>>>(
        w_dlt_hi, w_dlt_lo, nullptr, nullptr, xbuf, 128,
        nullptr, nullptr, delta, nullptr, 128, 128, 80000);
    mfma_gemm_kernel<0, 0, false><<<dim3(625, 1), blk, 0, stream>>>(
        w_gate_hi, w_gate_lo, nh_hi, nh_lo, nullptr, 384,
        gate_b, nullptr, gatepre, nullptr, 384, 128, 80000);
    enhance_fuse_kernel<<<dim3(1250), blk, 0, stream>>>(
        delta, gatepre, radar, gamma, nh_hi, nh_lo);

    // conv 3x3 (MFMA, split bf16) -> d_out; stats; batch-norm+relu in place
    conv_mfma_kernel<<<dim3(313, 2, 3), blk, 0, stream>>>(
        nh_hi, nh_lo, cwgt_hi, cwgt_lo, (float*)d_out);
    conv_stats_kernel<<<dim3(384), blk, 0, stream>>>((const float*)d_out);
    bn_relu_kernel<<<dim3(30000), blk, 0, stream>>>(
        (float*)d_out, bn_g, bn_b);
}